// Round 9
// baseline (1038.838 us; speedup 1.0000x reference)
//
#include <hip/hip_runtime.h>
#include <math.h>

typedef _Float16 half8 __attribute__((ext_vector_type(8)));
typedef _Float16 half4 __attribute__((ext_vector_type(4)));
typedef float    f32x4 __attribute__((ext_vector_type(4)));

#define T_DIM 36
#define N_AT 40
#define K_REAL 161
#define MT 11           // 11 M-tiles of 16 = 176 rows (161 real; pad tile dropped)
#define KSM 5           // 5 MFMA K-steps of 32 = 160; k=160 handled as rank-1 VALU
#define KS2 2           // DtY K-steps over t (36 -> 64)
#define B_DIM 2
#define F_DIM 20480
#define CB 16           // columns per block (one 16-wide MFMA N-tile)
#define NW 6            // waves per block; tiles/wave {2,2,2,2,2,1}
#define NTHREADS (NW * 64)   // 384
#define SETUP_T 512     // MUST be 512: frag builder needs tid>>3 to span 64 lanes
#define MAXIT 100
#define YK 200          // padded k-stride in y LDS (f16; 100 dwords)
#define YST 72          // Ystage t-stride (f16 units)

// ws layout (bytes):
//  [0..64): scalars  (float linv @0, float lam @4)
//  A-hat frags: idx = (Mt*KSM+ks)*2+term, 64 lanes x 8 f16 (1 KB each)
//  Dthat frags: idx = (Mt*KS2+ks2)*2+term
//  A160: 176 f32 (exact fp32 column 160 of A-hat)
#define WS_AFRAG_OFF 64
#define AFRAG_BYTES (MT * KSM * 2 * 1024)
#define WS_DFRAG_OFF (WS_AFRAG_OFF + AFRAG_BYTES)
#define DFRAG_BYTES (MT * KS2 * 2 * 1024)
#define WS_A160_OFF (WS_DFRAG_OFF + DFRAG_BYTES)

#define MFMA16(a, b, c) __builtin_amdgcn_mfma_f32_16x16x32_f16((a), (b), (c), 0, 0, 0)

__global__ void setup_kernel(const float* __restrict__ Drr,
                             const float* __restrict__ Dtheta,
                             float* __restrict__ ws) {
    __shared__ float Dl[K_REAL][T_DIM];   // normalized dictionary, [col k][t]
    __shared__ float red[SETUP_T];
    __shared__ float s_linv;
    int tid = threadIdx.x;

    // ---- build normalized dictionary columns ----
    if (tid < K_REAL) {
        float col[T_DIM];
        if (tid == 0) {
            for (int i = 0; i < T_DIM; ++i) col[i] = 1.0f;
        } else {
            int q = (tid - 1) / N_AT, n = (tid - 1) % N_AT;
            float r = Drr[n], th = Dtheta[n];
            float ri = 1.0f;
            for (int i = 0; i < T_DIM; ++i) {
                float c = cosf((float)i * th), s = sinf((float)i * th);
                float sign = (i & 1) ? -1.0f : 1.0f;
                float v;
                if (q == 0)      v = ri * c;
                else if (q == 1) v = sign * ri * c;
                else if (q == 2) v = ri * s;
                else             v = sign * ri * s;
                col[i] = v;
                ri *= r;
            }
        }
        float ss = 0.0f;
        for (int i = 0; i < T_DIM; ++i) ss += col[i] * col[i];
        float G = sqrtf(ss);
        float Ginv = (G == 0.0f) ? (1.0f / sqrtf((float)T_DIM)) : (1.0f / G);
        for (int i = 0; i < T_DIM; ++i) Dl[tid][i] = col[i] * Ginv;
    }
    __syncthreads();

    // ---- linv = 1 / frobenius(DtD) ----
    float local = 0.0f;
    for (int p = tid; p < K_REAL * K_REAL; p += SETUP_T) {
        int a = p / K_REAL, b = p % K_REAL;
        float dot = 0.0f;
        for (int i = 0; i < T_DIM; ++i) dot += Dl[a][i] * Dl[b][i];
        local += dot * dot;
    }
    red[tid] = local;
    __syncthreads();
    if (tid == 0) {
        float tot = 0.0f;
        for (int i = 0; i < SETUP_T; ++i) tot += red[i];
        float linv = 1.0f / sqrtf(tot);
        s_linv = linv;
        ws[0] = linv;
        ws[1] = 0.1f * linv;
    }
    __syncthreads();
    float linv = s_linv;

    // ---- A-hat fragments: A = I - linv * DtD, f16 hi/lo, A-operand layout ----
    // lane = tid>>3 (0..63 @512thr), e = tid&7 ; m = Mt*16+(lane&15) ; k = ks*32+(lane>>4)*8+e
    _Float16* wsA = (_Float16*)((char*)ws + WS_AFRAG_OFF);
    int lane = tid >> 3, e = tid & 7;
    int fm = lane & 15, fq = lane >> 4;
    for (int p = 0; p < MT * KSM; ++p) {
        int Mt = p / KSM, ks = p % KSM;
        int m = Mt * 16 + fm;
        int k = ks * 32 + fq * 8 + e;      // k <= 159: always real
        float v = 0.0f;
        if (m < K_REAL) {
            float dot = 0.0f;
            for (int t = 0; t < T_DIM; ++t) dot += Dl[m][t] * Dl[k][t];
            v = ((m == k) ? 1.0f : 0.0f) - linv * dot;
        }
        _Float16 h = (_Float16)v;
        _Float16 l = (_Float16)(v - (float)h);
        int base = (p * 2) * 512 + lane * 8 + e;
        wsA[base]       = h;
        wsA[base + 512] = l;
    }

    // ---- Dthat fragments: Dthat[k][t] = linv * D[t][k], A-operand layout over t ----
    _Float16* wsD = (_Float16*)((char*)ws + WS_DFRAG_OFF);
    for (int p = 0; p < MT * KS2; ++p) {
        int Mt = p / KS2, ks2 = p % KS2;
        int kr = Mt * 16 + fm;
        int t  = ks2 * 32 + fq * 8 + e;
        float v = (kr < K_REAL && t < T_DIM) ? linv * Dl[kr][t] : 0.0f;
        _Float16 h = (_Float16)v;
        _Float16 l = (_Float16)(v - (float)h);
        int base = (p * 2) * 512 + lane * 8 + e;
        wsD[base]       = h;
        wsD[base + 512] = l;
    }

    // ---- A160: exact fp32 column 160 of A-hat (rank-1 k=160 term) ----
    float* wsC = (float*)((char*)ws + WS_A160_OFF);
    if (tid < MT * 16) {
        int m = tid;
        float v = 0.0f;
        if (m < K_REAL) {
            float dot = 0.0f;
            for (int t = 0; t < T_DIM; ++t) dot += Dl[m][t] * Dl[160][t];
            v = ((m == 160) ? 1.0f : 0.0f) - linv * dot;
        }
        wsC[m] = v;
    }
}

__global__ void __launch_bounds__(NTHREADS, 3)
fista_mfma(const float* __restrict__ Y, const float* __restrict__ ws,
           float* __restrict__ out) {
    // ping-pong y in f16 hi/lo, [buf][part][col][k]  (25.6 KB; 2 blocks/CU by LDS)
    __shared__ __align__(16) _Float16 ybuf[2][2][CB][YK];

    const float lam = ((const float*)ws)[1];
    const half8* Afp = (const half8*)((const char*)ws + WS_AFRAG_OFF); // 64 half8/frag
    const half8* Dfp = (const half8*)((const char*)ws + WS_DFRAG_OFF);
    const float* A160 = (const float*)((const char*)ws + WS_A160_OFF);

    const int tid  = threadIdx.x;
    const int lane = tid & 63;
    const int mg   = __builtin_amdgcn_readfirstlane(tid >> 6); // 0..5 (M-group)
    const int mt0  = mg * 2;              // first owned tile
    const int mlc  = (mg == 5) ? 1 : 2;   // wave 5 owns tile 10 only
    const int quad = lane >> 4;
    const int cl   = lane & 15;           // local column 0..15

    const int blk = blockIdx.x;
    const int b   = blk / (F_DIM / CB);
    const int f0  = (blk % (F_DIM / CB)) * CB;

    // ---- stage Y (f16 hi/lo, [part][c][t]) into ybuf[1] area ----
    _Float16* Yst = &ybuf[1][0][0][0];
    const float* Yb = Y + (size_t)b * T_DIM * F_DIM + f0;
    for (int idx = tid; idx < 64 * CB; idx += NTHREADS) {
        int t = idx / CB, c = idx % CB;
        float v = (t < T_DIM) ? Yb[(size_t)t * F_DIM + c] : 0.0f;
        _Float16 h = (_Float16)v;
        _Float16 l = (_Float16)(v - (float)h);
        Yst[c * YST + t]            = h;
        Yst[CB * YST + c * YST + t] = l;
    }
    // ---- zero ybuf[0] (y = 0 initial iterate, incl. pad rows) ----
    int4* zb = (int4*)&ybuf[0][0][0][0];
    for (int idx = tid; idx < (2 * CB * YK * 2) / 16; idx += NTHREADS)
        zb[idx] = int4{0, 0, 0, 0};
    __syncthreads();

    // ---- DtY via MFMA (3-term split), lands directly in C-layout regs ----
    f32x4 dty[2];
    #pragma unroll
    for (int ml = 0; ml < 2; ++ml) dty[ml] = f32x4{0.f, 0.f, 0.f, 0.f};
    #pragma unroll
    for (int ks2 = 0; ks2 < KS2; ++ks2) {
        const _Float16* yp = Yst + cl * YST + ks2 * 32 + quad * 8;
        half8 yh = *(const half8*)yp;
        half8 yl = *(const half8*)(yp + CB * YST);
        #pragma unroll
        for (int ml = 0; ml < 2; ++ml) {
            if (ml < mlc) {
                int Mt = mt0 + ml;
                half8 dh = Dfp[((Mt * KS2 + ks2) * 2 + 0) * 64 + lane];
                half8 dl = Dfp[((Mt * KS2 + ks2) * 2 + 1) * 64 + lane];
                dty[ml] = MFMA16(dh, yh, dty[ml]);
                dty[ml] = MFMA16(dh, yl, dty[ml]);
                dty[ml] = MFMA16(dl, yh, dty[ml]);
            }
        }
    }
    __syncthreads();   // all waves done reading Yst before iter-0 writes ybuf[1]

    // ---- persistent A-hat fragments (2 tiles/wave -> 80 regs) + fp32 col 160
    //      STATIC indexing only (dynamic -> scratch spill, R6 lesson) ----
    half8 Af[2][KSM][2];
    float a160[2][4];
    #pragma unroll
    for (int ml = 0; ml < 2; ++ml) {
        if (ml < mlc) {
            #pragma unroll
            for (int ks = 0; ks < KSM; ++ks)
                #pragma unroll
                for (int term = 0; term < 2; ++term)
                    Af[ml][ks][term] =
                        Afp[(((mt0 + ml) * KSM + ks) * 2 + term) * 64 + lane];
            #pragma unroll
            for (int r = 0; r < 4; ++r)
                a160[ml][r] = A160[(mt0 + ml) * 16 + quad * 4 + r];
        }
    }

    float xold[2][4];
    #pragma unroll
    for (int ml = 0; ml < 2; ++ml)
        #pragma unroll
        for (int r = 0; r < 4; ++r) xold[ml][r] = 0.0f;

    float tm = 1.0f;
    int p = 0;
    for (int it = 0; it < MAXIT; ++it) {
        f32x4 acc[2];
        #pragma unroll
        for (int ml = 0; ml < 2; ++ml) acc[ml] = dty[ml];

        // rank-1 term: k = 160 (exact fp32)
        {
            float y160 = (float)ybuf[p][0][cl][160] + (float)ybuf[p][1][cl][160];
            #pragma unroll
            for (int ml = 0; ml < 2; ++ml)
                if (ml < mlc)
                    #pragma unroll
                    for (int r = 0; r < 4; ++r)
                        acc[ml][r] += a160[ml][r] * y160;
        }

        // main K sweep: 3 MFMA per (tile,ks) — Ah*yh + Ah*yl + Al*yh
        #pragma unroll
        for (int ks = 0; ks < KSM; ++ks) {
            const _Float16* yp = &ybuf[p][0][cl][ks * 32 + quad * 8];
            half8 yh = *(const half8*)yp;
            half8 yl = *(const half8*)(yp + CB * YK);
            #pragma unroll
            for (int ml = 0; ml < 2; ++ml) {
                if (ml < mlc) {
                    acc[ml] = MFMA16(Af[ml][ks][0], yh, acc[ml]);
                    acc[ml] = MFMA16(Af[ml][ks][0], yl, acc[ml]);
                    acc[ml] = MFMA16(Af[ml][ks][1], yh, acc[ml]);
                }
            }
        }

        float tn = 0.5f * (1.0f + sqrtf(1.0f + 4.0f * tm * tm));
        float tt = (tm - 1.0f) / tn;
        tm = tn;

        #pragma unroll
        for (int ml = 0; ml < 2; ++ml) {
            if (ml < mlc) {
                half4 hv, lv;
                #pragma unroll
                for (int r = 0; r < 4; ++r) {
                    float v  = acc[ml][r];          // = A*y + DtY
                    float s  = fmaxf(fabsf(v) - lam, 0.0f);
                    float xn = copysignf(s, v);
                    float yn = (1.0f + tt) * xn - tt * xold[ml][r];
                    xold[ml][r] = xn;
                    _Float16 h = (_Float16)yn;
                    hv[r] = h;
                    lv[r] = (_Float16)(yn - (float)h);
                }
                int k0 = (mt0 + ml) * 16 + quad * 4;
                *(half4*)&ybuf[1 - p][0][cl][k0] = hv;
                *(half4*)&ybuf[1 - p][1][cl][k0] = lv;
            }
        }
        __syncthreads();
        p ^= 1;
    }

    // ---- output x (fp32) ----
    float* ob = out + (size_t)b * K_REAL * F_DIM + f0 + cl;
    #pragma unroll
    for (int ml = 0; ml < 2; ++ml)
        if (ml < mlc)
            #pragma unroll
            for (int r = 0; r < 4; ++r) {
                int k = (mt0 + ml) * 16 + quad * 4 + r;
                if (k < K_REAL) ob[(size_t)k * F_DIM] = xold[ml][r];
            }
}

extern "C" void kernel_launch(void* const* d_in, const int* in_sizes, int n_in,
                              void* d_out, int out_size, void* d_ws, size_t ws_size,
                              hipStream_t stream) {
    const float* x      = (const float*)d_in[0];
    const float* Drr    = (const float*)d_in[1];
    const float* Dtheta = (const float*)d_in[2];
    float* out = (float*)d_out;
    float* ws  = (float*)d_ws;

    hipLaunchKernelGGL(setup_kernel, dim3(1), dim3(SETUP_T), 0, stream,
                       Drr, Dtheta, ws);
    hipLaunchKernelGGL(fista_mfma, dim3((B_DIM * F_DIM) / CB), dim3(NTHREADS),
                       0, stream, x, ws, out);
}

// Round 10
// 682.503 us; speedup vs baseline: 1.5221x; 1.5221x over previous
//
#include <hip/hip_runtime.h>
#include <math.h>

typedef _Float16 half8 __attribute__((ext_vector_type(8)));
typedef _Float16 half4 __attribute__((ext_vector_type(4)));
typedef float    f32x4 __attribute__((ext_vector_type(4)));

#define T_DIM 36
#define N_AT 40
#define K_REAL 161
#define MT 11           // 11 M-tiles of 16 = 176 rows (161 real; pad tile dropped)
#define KSM 5           // 5 MFMA K-steps of 32 = 160; k=160 handled as rank-1 VALU
#define KS2 2           // DtY K-steps over t (36 -> 64)
#define B_DIM 2
#define F_DIM 20480
#define CB 32           // columns per block = 2 N-tiles of 16 per wave
#define NG 2            // N-tiles per wave
#define NTHREADS 256    // 4 waves; 2 blocks/CU (register-limited 2 waves/SIMD)
#define SETUP_T 512     // MUST be 512: frag builder needs tid>>3 to span 64 lanes
#define MAXIT 100
#define YK 200          // padded k-stride in y LDS (f16; 100 dwords)
#define YST 72          // Ystage t-stride (f16 units)

// ws layout (bytes):
//  [0..64): scalars  (float linv @0, float lam @4)
//  A-hat frags: idx = (Mt*KSM+ks)*2+term, 64 lanes x 8 f16 (1 KB each)
//  Dthat frags: idx = (Mt*KS2+ks2)*2+term
//  A160: 176 f32 (exact fp32 column 160 of A-hat)
#define WS_AFRAG_OFF 64
#define AFRAG_BYTES (MT * KSM * 2 * 1024)
#define WS_DFRAG_OFF (WS_AFRAG_OFF + AFRAG_BYTES)
#define DFRAG_BYTES (MT * KS2 * 2 * 1024)
#define WS_A160_OFF (WS_DFRAG_OFF + DFRAG_BYTES)

#define MFMA16(a, b, c) __builtin_amdgcn_mfma_f32_16x16x32_f16((a), (b), (c), 0, 0, 0)

__global__ void setup_kernel(const float* __restrict__ Drr,
                             const float* __restrict__ Dtheta,
                             float* __restrict__ ws) {
    __shared__ float Dl[K_REAL][T_DIM];   // normalized dictionary, [col k][t]
    __shared__ float red[SETUP_T];
    __shared__ float s_linv;
    int tid = threadIdx.x;

    // ---- build normalized dictionary columns ----
    if (tid < K_REAL) {
        float col[T_DIM];
        if (tid == 0) {
            for (int i = 0; i < T_DIM; ++i) col[i] = 1.0f;
        } else {
            int q = (tid - 1) / N_AT, n = (tid - 1) % N_AT;
            float r = Drr[n], th = Dtheta[n];
            float ri = 1.0f;
            for (int i = 0; i < T_DIM; ++i) {
                float c = cosf((float)i * th), s = sinf((float)i * th);
                float sign = (i & 1) ? -1.0f : 1.0f;
                float v;
                if (q == 0)      v = ri * c;
                else if (q == 1) v = sign * ri * c;
                else if (q == 2) v = ri * s;
                else             v = sign * ri * s;
                col[i] = v;
                ri *= r;
            }
        }
        float ss = 0.0f;
        for (int i = 0; i < T_DIM; ++i) ss += col[i] * col[i];
        float G = sqrtf(ss);
        float Ginv = (G == 0.0f) ? (1.0f / sqrtf((float)T_DIM)) : (1.0f / G);
        for (int i = 0; i < T_DIM; ++i) Dl[tid][i] = col[i] * Ginv;
    }
    __syncthreads();

    // ---- linv = 1 / frobenius(DtD) ----
    float local = 0.0f;
    for (int p = tid; p < K_REAL * K_REAL; p += SETUP_T) {
        int a = p / K_REAL, b = p % K_REAL;
        float dot = 0.0f;
        for (int i = 0; i < T_DIM; ++i) dot += Dl[a][i] * Dl[b][i];
        local += dot * dot;
    }
    red[tid] = local;
    __syncthreads();
    if (tid == 0) {
        float tot = 0.0f;
        for (int i = 0; i < SETUP_T; ++i) tot += red[i];
        float linv = 1.0f / sqrtf(tot);
        s_linv = linv;
        ws[0] = linv;
        ws[1] = 0.1f * linv;
    }
    __syncthreads();
    float linv = s_linv;

    // ---- A-hat fragments: A = I - linv * DtD, f16 hi/lo, A-operand layout ----
    // lane = tid>>3 (0..63 @512thr), e = tid&7 ; m = Mt*16+(lane&15) ; k = ks*32+(lane>>4)*8+e
    _Float16* wsA = (_Float16*)((char*)ws + WS_AFRAG_OFF);
    int lane = tid >> 3, e = tid & 7;
    int fm = lane & 15, fq = lane >> 4;
    for (int p = 0; p < MT * KSM; ++p) {
        int Mt = p / KSM, ks = p % KSM;
        int m = Mt * 16 + fm;
        int k = ks * 32 + fq * 8 + e;      // k <= 159: always real
        float v = 0.0f;
        if (m < K_REAL) {
            float dot = 0.0f;
            for (int t = 0; t < T_DIM; ++t) dot += Dl[m][t] * Dl[k][t];
            v = ((m == k) ? 1.0f : 0.0f) - linv * dot;
        }
        _Float16 h = (_Float16)v;
        _Float16 l = (_Float16)(v - (float)h);
        int base = (p * 2) * 512 + lane * 8 + e;
        wsA[base]       = h;
        wsA[base + 512] = l;
    }

    // ---- Dthat fragments: Dthat[k][t] = linv * D[t][k], A-operand layout over t ----
    _Float16* wsD = (_Float16*)((char*)ws + WS_DFRAG_OFF);
    for (int p = 0; p < MT * KS2; ++p) {
        int Mt = p / KS2, ks2 = p % KS2;
        int kr = Mt * 16 + fm;
        int t  = ks2 * 32 + fq * 8 + e;
        float v = (kr < K_REAL && t < T_DIM) ? linv * Dl[kr][t] : 0.0f;
        _Float16 h = (_Float16)v;
        _Float16 l = (_Float16)(v - (float)h);
        int base = (p * 2) * 512 + lane * 8 + e;
        wsD[base]       = h;
        wsD[base + 512] = l;
    }

    // ---- A160: exact fp32 column 160 of A-hat (rank-1 k=160 term; A symmetric) ----
    float* wsC = (float*)((char*)ws + WS_A160_OFF);
    if (tid < MT * 16) {
        int m = tid;
        float v = 0.0f;
        if (m < K_REAL) {
            float dot = 0.0f;
            for (int t = 0; t < T_DIM; ++t) dot += Dl[m][t] * Dl[160][t];
            v = ((m == 160) ? 1.0f : 0.0f) - linv * dot;
        }
        wsC[m] = v;
    }
}

__global__ void __launch_bounds__(NTHREADS, 2)
fista_mfma(const float* __restrict__ Y, const float* __restrict__ ws,
           float* __restrict__ out) {
    // ping-pong y in f16 hi/lo, [buf][part][col][k]  (51.2 KB; regs limit to 2 blk/CU)
    __shared__ __align__(16) _Float16 ybuf[2][2][CB][YK];

    const float lam = ((const float*)ws)[1];
    const half8* Afp = (const half8*)((const char*)ws + WS_AFRAG_OFF); // 64 half8/frag
    const half8* Dfp = (const half8*)((const char*)ws + WS_DFRAG_OFF);
    const float* A160 = (const float*)((const char*)ws + WS_A160_OFF);

    const int tid  = threadIdx.x;
    const int lane = tid & 63;
    const int mg   = __builtin_amdgcn_readfirstlane(tid >> 6); // 0..3 (M-group)
    const int mlc  = (mg == 3) ? 2 : 3;   // wave 3 owns tiles 9,10 only
    const int quad = lane >> 4;
    const int cl   = lane & 15;           // column within an N-tile

    const int blk = blockIdx.x;
    const int b   = blk / (F_DIM / CB);
    const int f0  = (blk % (F_DIM / CB)) * CB;

    // ---- stage Y (f16 hi/lo, [part][c][t]) into ybuf[1] area ----
    _Float16* Yst = &ybuf[1][0][0][0];    // 2*CB*YST*2 = 9216 B of the 25.6 KB half
    const float* Yb = Y + (size_t)b * T_DIM * F_DIM + f0;
    for (int idx = tid; idx < 64 * CB; idx += NTHREADS) {
        int t = idx / CB, c = idx % CB;
        float v = (t < T_DIM) ? Yb[(size_t)t * F_DIM + c] : 0.0f;
        _Float16 h = (_Float16)v;
        _Float16 l = (_Float16)(v - (float)h);
        Yst[c * YST + t]            = h;
        Yst[CB * YST + c * YST + t] = l;
    }
    // ---- zero ybuf[0] (y = 0 initial iterate, incl. pad rows) ----
    int4* zb = (int4*)&ybuf[0][0][0][0];
    for (int idx = tid; idx < (2 * CB * YK * 2) / 16; idx += NTHREADS)
        zb[idx] = int4{0, 0, 0, 0};
    __syncthreads();

    // ---- DtY via MFMA (3-term split), per N-tile, lands in C-layout regs ----
    f32x4 dty[3][NG];
    #pragma unroll
    for (int ml = 0; ml < 3; ++ml)
        #pragma unroll
        for (int ng = 0; ng < NG; ++ng) dty[ml][ng] = f32x4{0.f, 0.f, 0.f, 0.f};
    #pragma unroll
    for (int ks2 = 0; ks2 < KS2; ++ks2) {
        #pragma unroll
        for (int ng = 0; ng < NG; ++ng) {
            const _Float16* yp = Yst + (ng * 16 + cl) * YST + ks2 * 32 + quad * 8;
            half8 yh = *(const half8*)yp;
            half8 yl = *(const half8*)(yp + CB * YST);
            #pragma unroll
            for (int ml = 0; ml < 3; ++ml) {
                if (ml < mlc) {
                    int Mt = mg * 3 + ml;
                    half8 dh = Dfp[((Mt * KS2 + ks2) * 2 + 0) * 64 + lane];
                    half8 dl = Dfp[((Mt * KS2 + ks2) * 2 + 1) * 64 + lane];
                    dty[ml][ng] = MFMA16(dh, yh, dty[ml][ng]);
                    dty[ml][ng] = MFMA16(dh, yl, dty[ml][ng]);
                    dty[ml][ng] = MFMA16(dl, yh, dty[ml][ng]);
                }
            }
        }
    }
    __syncthreads();   // all waves done reading Yst before iter-0 writes ybuf[1]

    // ---- persistent A-hat fragments (120 regs) + fp32 col 160
    //      STATIC indexing only (dynamic -> scratch spill, R6 lesson) ----
    half8 Af[3][KSM][2];
    float a160[3][4];
    #pragma unroll
    for (int ml = 0; ml < 3; ++ml) {
        if (ml < mlc) {
            #pragma unroll
            for (int ks = 0; ks < KSM; ++ks)
                #pragma unroll
                for (int term = 0; term < 2; ++term)
                    Af[ml][ks][term] =
                        Afp[(((mg * 3 + ml) * KSM + ks) * 2 + term) * 64 + lane];
            #pragma unroll
            for (int r = 0; r < 4; ++r)
                a160[ml][r] = A160[(mg * 3 + ml) * 16 + quad * 4 + r];
        }
    }

    float xold[3][NG][4];
    #pragma unroll
    for (int ml = 0; ml < 3; ++ml)
        #pragma unroll
        for (int ng = 0; ng < NG; ++ng)
            #pragma unroll
            for (int r = 0; r < 4; ++r) xold[ml][ng][r] = 0.0f;

    float tm = 1.0f;
    int p = 0;
    for (int it = 0; it < MAXIT; ++it) {
        f32x4 acc[3][NG];
        #pragma unroll
        for (int ml = 0; ml < 3; ++ml)
            #pragma unroll
            for (int ng = 0; ng < NG; ++ng) acc[ml][ng] = dty[ml][ng];

        // rank-1 term: k = 160 (exact fp32)
        #pragma unroll
        for (int ng = 0; ng < NG; ++ng) {
            float y160 = (float)ybuf[p][0][ng * 16 + cl][160]
                       + (float)ybuf[p][1][ng * 16 + cl][160];
            #pragma unroll
            for (int ml = 0; ml < 3; ++ml)
                if (ml < mlc)
                    #pragma unroll
                    for (int r = 0; r < 4; ++r)
                        acc[ml][ng][r] += a160[ml][r] * y160;
        }

        // main K sweep: per (ks,ng) one yh+yl load pair feeds 3 MFMA x mlc tiles
        #pragma unroll
        for (int ks = 0; ks < KSM; ++ks) {
            #pragma unroll
            for (int ng = 0; ng < NG; ++ng) {
                const _Float16* yp = &ybuf[p][0][ng * 16 + cl][ks * 32 + quad * 8];
                half8 yh = *(const half8*)yp;
                half8 yl = *(const half8*)(yp + CB * YK);
                #pragma unroll
                for (int ml = 0; ml < 3; ++ml) {
                    if (ml < mlc) {
                        acc[ml][ng] = MFMA16(Af[ml][ks][0], yh, acc[ml][ng]);
                        acc[ml][ng] = MFMA16(Af[ml][ks][0], yl, acc[ml][ng]);
                        acc[ml][ng] = MFMA16(Af[ml][ks][1], yh, acc[ml][ng]);
                    }
                }
            }
        }

        float tn = 0.5f * (1.0f + sqrtf(1.0f + 4.0f * tm * tm));
        float tt = (tm - 1.0f) / tn;
        tm = tn;

        #pragma unroll
        for (int ml = 0; ml < 3; ++ml) {
            if (ml < mlc) {
                #pragma unroll
                for (int ng = 0; ng < NG; ++ng) {
                    half4 hv, lv;
                    #pragma unroll
                    for (int r = 0; r < 4; ++r) {
                        float v  = acc[ml][ng][r];      // = A*y + DtY
                        float s  = fmaxf(fabsf(v) - lam, 0.0f);
                        float xn = copysignf(s, v);
                        float yn = (1.0f + tt) * xn - tt * xold[ml][ng][r];
                        xold[ml][ng][r] = xn;
                        _Float16 h = (_Float16)yn;
                        hv[r] = h;
                        lv[r] = (_Float16)(yn - (float)h);
                    }
                    int k0 = (mg * 3 + ml) * 16 + quad * 4;
                    *(half4*)&ybuf[1 - p][0][ng * 16 + cl][k0] = hv;
                    *(half4*)&ybuf[1 - p][1][ng * 16 + cl][k0] = lv;
                }
            }
        }
        __syncthreads();
        p ^= 1;
    }

    // ---- output x (fp32) ----
    #pragma unroll
    for (int ng = 0; ng < NG; ++ng) {
        float* ob = out + (size_t)b * K_REAL * F_DIM + f0 + ng * 16 + cl;
        #pragma unroll
        for (int ml = 0; ml < 3; ++ml)
            if (ml < mlc)
                #pragma unroll
                for (int r = 0; r < 4; ++r) {
                    int k = (mg * 3 + ml) * 16 + quad * 4 + r;
                    if (k < K_REAL) ob[(size_t)k * F_DIM] = xold[ml][ng][r];
                }
    }
}

extern "C" void kernel_launch(void* const* d_in, const int* in_sizes, int n_in,
                              void* d_out, int out_size, void* d_ws, size_t ws_size,
                              hipStream_t stream) {
    const float* x      = (const float*)d_in[0];
    const float* Drr    = (const float*)d_in[1];
    const float* Dtheta = (const float*)d_in[2];
    float* out = (float*)d_out;
    float* ws  = (float*)d_ws;

    hipLaunchKernelGGL(setup_kernel, dim3(1), dim3(SETUP_T), 0, stream,
                       Drr, Dtheta, ws);
    hipLaunchKernelGGL(fista_mfma, dim3((B_DIM * F_DIM) / CB), dim3(NTHREADS),
                       0, stream, x, ws, out);
}